// Round 10
// baseline (53.259 us; speedup 1.0000x reference)
//
#include <hip/hip_runtime.h>

typedef float f32x4 __attribute__((ext_vector_type(4)));
typedef __bf16 bf16x8 __attribute__((ext_vector_type(8)));
typedef __bf16 bf16x4 __attribute__((ext_vector_type(4)));

#define T_ 2048
#define DE 1024
#define DQ 64
#define SCALE 0.125f

#define GL16(gp, lp)                                                        \
  __builtin_amdgcn_global_load_lds(                                         \
      (const __attribute__((address_space(1))) void*)(gp),                  \
      (__attribute__((address_space(3))) void*)(lp), 16, 0, 0)

#define WAITVM(N) asm volatile("s_waitcnt vmcnt(" #N ")" ::: "memory")

// ---------- kernel 0: pack W (3x [1024][64] f32) into fragment-major bf16 Wf.
// Wf[(kc*12 + t)*64 + lane][8]: elem j = W[kc*32+(lane>>4)*8+j][(t&3)*16+(lane&15)],
// matrix = t>>2, kc = k/32.  (validated R5-R9)
__global__ __launch_bounds__(256) void kw_pack(
    const float* __restrict__ Wq, const float* __restrict__ Wk,
    const float* __restrict__ Wv, __bf16* __restrict__ Wf)
{
  int tid = blockIdx.x * 256 + threadIdx.x;   // 0..24575 = f*64 + lane
  int lane = tid & 63, f = tid >> 6;
  int t = f % 12, kc = f / 12;
  const float* W = (t < 4) ? Wq : ((t < 8) ? Wk : Wv);
  int nl = (t & 3) * 16 + (lane & 15);
  int k0 = kc * 32 + (lane >> 4) * 8;
  bf16x8 v;
#pragma unroll
  for (int j = 0; j < 8; ++j) v[j] = (__bf16)W[(size_t)(k0 + j) * 64 + nl];
  *(bf16x8*)(Wf + (size_t)tid * 8) = v;
}

// ---------- kernel 1: QKV projection. Block = 32 m-rows, 4 waves = 2 msub x 2 ngrp.
// A (x) via global_load_lds, 3 buffers, 2 steps ahead. B (Wf) REGISTER-direct from
// L1/L2, double-buffered, issued in need-order BEFORE the A stage so steady
// WAITVM(2) retires {A(ks),B(ks)} and keeps A(ks+1) in flight. LDS = A only.
__global__ __launch_bounds__(256) void kproj(
    const float* __restrict__ x, const __bf16* __restrict__ Wf,
    __bf16* __restrict__ Qb, __bf16* __restrict__ Kb, __bf16* __restrict__ Vt)
{
  __shared__ float xs[3][32 * 64];            // 3 x 8 KB
  const int tid = threadIdx.x;
  const int lane = tid & 63;
  const int w = tid >> 6;
  const int col = lane & 15, g = lane >> 4;
  const int msub = w & 1;                     // 16-row half
  const int ng6 = (w >> 1) * 6;               // first n-tile of this wave's group
  const int mbase = blockIdx.x * 32;

  // A staging: 8 chunks of 1KB/step; wave stages chunks q = w*2+cc.
  // chunk q: row = q*4+(l>>4), slot l&15; source pre-swizzled by ((row&7)<<4).
  size_t gsrcA[2];
  int ldstA[2];
#pragma unroll
  for (int cc = 0; cc < 2; ++cc) {
    int q = w * 2 + cc;
    int row = q * 4 + (lane >> 4);
    int kbyte = ((lane & 15) * 16) ^ ((row & 7) << 4);
    gsrcA[cc] = (size_t)(mbase + row) * 4096 + (size_t)kbyte;
    ldstA[cc] = q * 1024 + lane * 16;
  }

  f32x4 acc[6];
#pragma unroll
  for (int i = 0; i < 6; ++i) acc[i] = (f32x4){0.f, 0.f, 0.f, 0.f};

  const char* xb = (const char*)x;
  const char* wb = (const char*)Wf;
  const int arow = msub * 16 + col;
  const int sw = (arow & 7) << 4;

  bf16x8 bX[2][6], bY[2][6];                  // B double-buffer (static indexing)

#define STAGE_A(ks)                                                         \
  {                                                                         \
    char* lb = (char*)&xs[(ks) % 3][0];                                     \
    _Pragma("unroll")                                                       \
    for (int cc = 0; cc < 2; ++cc)                                          \
      GL16(xb + gsrcA[cc] + (size_t)(ks) * 256, lb + ldstA[cc]);            \
  }
#define LOADB(ks, B)                                                        \
  {                                                                         \
    _Pragma("unroll")                                                       \
    for (int kh = 0; kh < 2; ++kh)                                          \
      _Pragma("unroll")                                                     \
      for (int ii = 0; ii < 6; ++ii)                                        \
        B[kh][ii] = *(const bf16x8*)(wb +                                   \
            ((size_t)(((ks) * 2 + kh) * 12 + ng6 + ii) * 64 + lane) * 16);  \
  }
#define KSTEP(ks, B)                                                        \
  {                                                                         \
    const char* abase = (const char*)&xs[(ks) % 3][0] + arow * 256;         \
    _Pragma("unroll")                                                       \
    for (int kh = 0; kh < 2; ++kh) {                                        \
      int kb = kh * 128 + g * 32;                                           \
      f32x4 a0 = *(const f32x4*)(abase + (kb ^ sw));                        \
      f32x4 a1 = *(const f32x4*)(abase + ((kb + 16) ^ sw));                 \
      bf16x8 af;                                                            \
      _Pragma("unroll")                                                     \
      for (int j = 0; j < 4; ++j) { af[j] = (__bf16)a0[j]; af[4 + j] = (__bf16)a1[j]; } \
      _Pragma("unroll")                                                     \
      for (int ii = 0; ii < 6; ++ii)                                        \
        acc[ii] = __builtin_amdgcn_mfma_f32_16x16x32_bf16(af, B[kh][ii], acc[ii], 0, 0, 0); \
    }                                                                       \
  }
// issue order inside an iter: B(ks+1) FIRST, then A(ks+2) (need-order for the FIFO)
#define ITER(ks, vm, doB, doA, BLOAD, BUSE)                                 \
  WAITVM(vm);                                                               \
  __builtin_amdgcn_s_barrier();                                             \
  __builtin_amdgcn_sched_barrier(0);                                        \
  if (doB) LOADB((ks) + 1, BLOAD);                                          \
  __builtin_amdgcn_sched_barrier(0);                                        \
  if (doA) STAGE_A((ks) + 2);                                               \
  __builtin_amdgcn_sched_barrier(0);                                        \
  KSTEP(ks, BUSE);

  // prologue in need-order: A(0), B(0), A(1)
  STAGE_A(0);
  LOADB(0, bX);
  STAGE_A(1);

  ITER(0, 2, 1, 1, bY, bX)   ITER(1, 2, 1, 1, bX, bY)
  ITER(2, 2, 1, 1, bY, bX)   ITER(3, 2, 1, 1, bX, bY)
  ITER(4, 2, 1, 1, bY, bX)   ITER(5, 2, 1, 1, bX, bY)
  ITER(6, 2, 1, 1, bY, bX)   ITER(7, 2, 1, 1, bX, bY)
  ITER(8, 2, 1, 1, bY, bX)   ITER(9, 2, 1, 1, bX, bY)
  ITER(10, 2, 1, 1, bY, bX)  ITER(11, 2, 1, 1, bX, bY)
  ITER(12, 2, 1, 1, bY, bX)  ITER(13, 2, 1, 1, bX, bY)
  ITER(14, 2, 1, 0, bY, bX)  ITER(15, 0, 0, 0, bX, bY)

#undef ITER
#undef KSTEP
#undef LOADB
#undef STAGE_A

  // epilogue: D layout row = g*4+r (within 16-row m-sub), col = ti*16 + col
  const int b = mbase >> 11;
  const int mrow = mbase + msub * 16 + g * 4;
  const int trow = (mbase & 2047) + msub * 16 + g * 4;
#pragma unroll
  for (int ii = 0; ii < 6; ++ii) {
    int ti = ng6 + ii;
    if (ti < 8) {
      __bf16* dst = (ti < 4) ? Qb : Kb;
      int c = (ti & 3) * 16 + col;
#pragma unroll
      for (int r = 0; r < 4; ++r)
        dst[(size_t)(mrow + r) * DQ + c] = (__bf16)acc[ii][r];
    } else {
      int d = (ti - 8) * 16 + col;
      bf16x4 v;
#pragma unroll
      for (int r = 0; r < 4; ++r) v[r] = (__bf16)acc[ii][r];
      *(bf16x4*)(Vt + ((size_t)(b * DQ + d)) * T_ + trow) = v;
    }
  }
}

// ---------- kernel 2: causal flash attention. Block = 32 q-rows, 4 waves split KV
// (KVB=64), LDS combine. + defer-max (THR=8) + setprio around MFMA clusters.
__global__ __launch_bounds__(256) void kattn(
    const __bf16* __restrict__ Qb, const __bf16* __restrict__ Kb,
    const __bf16* __restrict__ Vt, float* __restrict__ out)
{
  __shared__ float accs[4][32][68];
  __shared__ float mls[4][2][32];
  __shared__ __bf16 plds[4][2][16][72];

  const int tid = threadIdx.x;
  const int lane = tid & 63;
  const int w = tid >> 6;
  const int col = lane & 15, g = lane >> 4;
  const int b = blockIdx.x & 7;
  const int jq = 63 - (blockIdx.x >> 3);
  const int qbase = jq * 32;

  bf16x8 qa[2][2];
#pragma unroll
  for (int mt = 0; mt < 2; ++mt) {
    const __bf16* Qp = Qb + (size_t)(b * T_ + qbase + mt * 16 + col) * DQ + g * 8;
    qa[mt][0] = *(const bf16x8*)(Qp);
    qa[mt][1] = *(const bf16x8*)(Qp + 32);
  }

  const __bf16* Kbb = Kb + (size_t)b * T_ * DQ;
  const __bf16* Vbb = Vt + (size_t)b * DQ * T_;

  f32x4 acc[2][4];
#pragma unroll
  for (int mt = 0; mt < 2; ++mt)
#pragma unroll
    for (int dt = 0; dt < 4; ++dt) acc[mt][dt] = (f32x4){0.f,0.f,0.f,0.f};
  float mrun[2][4], lsum[2][4];
#pragma unroll
  for (int mt = 0; mt < 2; ++mt)
#pragma unroll
    for (int r = 0; r < 4; ++r) { mrun[mt][r] = -1e30f; lsum[mt][r] = 0.f; }

  const int nb = (jq >> 1) + 1;
  for (int it = w; it < nb; it += 4) {
    const int nbase = it * 64;

    bf16x8 kf_[4][2];
#pragma unroll
    for (int nt = 0; nt < 4; ++nt) {
      const __bf16* Kp = Kbb + (size_t)(nbase + nt * 16 + col) * DQ + g * 8;
      kf_[nt][0] = *(const bf16x8*)(Kp);
      kf_[nt][1] = *(const bf16x8*)(Kp + 32);
    }

    f32x4 s[2][4];
    __builtin_amdgcn_s_setprio(1);
#pragma unroll
    for (int mt = 0; mt < 2; ++mt)
#pragma unroll
      for (int nt = 0; nt < 4; ++nt) {
        f32x4 t = __builtin_amdgcn_mfma_f32_16x16x32_bf16(qa[mt][0], kf_[nt][0],
                                                          (f32x4){0.f,0.f,0.f,0.f}, 0, 0, 0);
        s[mt][nt] = __builtin_amdgcn_mfma_f32_16x16x32_bf16(qa[mt][1], kf_[nt][1], t, 0, 0, 0);
      }
    __builtin_amdgcn_s_setprio(0);

    bf16x8 vf[4][2];
#pragma unroll
    for (int dt = 0; dt < 4; ++dt) {
      const __bf16* Vp = Vbb + (size_t)(dt * 16 + col) * T_ + nbase + g * 8;
      vf[dt][0] = *(const bf16x8*)(Vp);
      vf[dt][1] = *(const bf16x8*)(Vp + 32);
    }

#pragma unroll
    for (int mt = 0; mt < 2; ++mt)
#pragma unroll
      for (int nt = 0; nt < 4; ++nt)
#pragma unroll
        for (int r = 0; r < 4; ++r) s[mt][nt][r] *= SCALE;
    if (it == nb - 1) {
#pragma unroll
      for (int mt = 0; mt < 2; ++mt)
#pragma unroll
        for (int nt = 0; nt < 4; ++nt)
#pragma unroll
          for (int r = 0; r < 4; ++r)
            if (nbase + nt * 16 + col > qbase + mt * 16 + g * 4 + r) s[mt][nt][r] = -1e30f;
    }

    // defer-max: in-lane tile max, full cross-lane reduce only when it grew > THR
    float pmax[2][4];
#pragma unroll
    for (int mt = 0; mt < 2; ++mt)
#pragma unroll
      for (int r = 0; r < 4; ++r)
        pmax[mt][r] = fmaxf(fmaxf(s[mt][0][r], s[mt][1][r]), fmaxf(s[mt][2][r], s[mt][3][r]));
    bool need = false;
#pragma unroll
    for (int mt = 0; mt < 2; ++mt)
#pragma unroll
      for (int r = 0; r < 4; ++r)
        need = need || (pmax[mt][r] > mrun[mt][r] + 8.f);

    if (__any(need)) {
      float mv[2][4];
#pragma unroll
      for (int mt = 0; mt < 2; ++mt)
#pragma unroll
        for (int r = 0; r < 4; ++r) mv[mt][r] = pmax[mt][r];
#pragma unroll
      for (int sh = 1; sh <= 8; sh <<= 1)
#pragma unroll
        for (int mt = 0; mt < 2; ++mt)
#pragma unroll
          for (int r = 0; r < 4; ++r) mv[mt][r] = fmaxf(mv[mt][r], __shfl_xor(mv[mt][r], sh, 64));
#pragma unroll
      for (int mt = 0; mt < 2; ++mt)
#pragma unroll
        for (int r = 0; r < 4; ++r) {
          float mn = fmaxf(mrun[mt][r], mv[mt][r]);
          float rs = __expf(mrun[mt][r] - mn);
          mrun[mt][r] = mn;
          float ps = 0.f;
#pragma unroll
          for (int nt = 0; nt < 4; ++nt) {
            s[mt][nt][r] = __expf(s[mt][nt][r] - mn);
            ps += s[mt][nt][r];
          }
          lsum[mt][r] = lsum[mt][r] * rs + ps;
#pragma unroll
          for (int dt = 0; dt < 4; ++dt) acc[mt][dt][r] *= rs;
        }
    } else {
      // fast path: keep mrun; P bounded by e^8, no rescale needed
#pragma unroll
      for (int mt = 0; mt < 2; ++mt)
#pragma unroll
        for (int r = 0; r < 4; ++r) {
          float ps = 0.f;
#pragma unroll
          for (int nt = 0; nt < 4; ++nt) {
            s[mt][nt][r] = __expf(s[mt][nt][r] - mrun[mt][r]);
            ps += s[mt][nt][r];
          }
          lsum[mt][r] += ps;
        }
    }

#pragma unroll
    for (int mt = 0; mt < 2; ++mt)
#pragma unroll
      for (int nt = 0; nt < 4; ++nt)
#pragma unroll
        for (int r = 0; r < 4; ++r)
          plds[w][mt][g * 4 + r][nt * 16 + col] = (__bf16)s[mt][nt][r];

    bf16x8 pa[2][2];
#pragma unroll
    for (int mt = 0; mt < 2; ++mt) {
      pa[mt][0] = *(const bf16x8*)&plds[w][mt][col][g * 8];
      pa[mt][1] = *(const bf16x8*)&plds[w][mt][col][32 + g * 8];
    }

    __builtin_amdgcn_s_setprio(1);
#pragma unroll
    for (int mt = 0; mt < 2; ++mt)
#pragma unroll
      for (int dt = 0; dt < 4; ++dt) {
        f32x4 t = __builtin_amdgcn_mfma_f32_16x16x32_bf16(pa[mt][0], vf[dt][0], acc[mt][dt], 0, 0, 0);
        acc[mt][dt] = __builtin_amdgcn_mfma_f32_16x16x32_bf16(pa[mt][1], vf[dt][1], t, 0, 0, 0);
      }
    __builtin_amdgcn_s_setprio(0);
  }

#pragma unroll
  for (int sh = 1; sh <= 8; sh <<= 1)
#pragma unroll
    for (int mt = 0; mt < 2; ++mt)
#pragma unroll
      for (int r = 0; r < 4; ++r) lsum[mt][r] += __shfl_xor(lsum[mt][r], sh, 64);

#pragma unroll
  for (int mt = 0; mt < 2; ++mt)
#pragma unroll
    for (int r = 0; r < 4; ++r) {
      int row = mt * 16 + g * 4 + r;
      accs[w][row][col]      = acc[mt][0][r];
      accs[w][row][col + 16] = acc[mt][1][r];
      accs[w][row][col + 32] = acc[mt][2][r];
      accs[w][row][col + 48] = acc[mt][3][r];
      if (col == 0) { mls[w][0][row] = mrun[mt][r]; mls[w][1][row] = lsum[mt][r]; }
    }
  __syncthreads();

#pragma unroll
  for (int pass = 0; pass < 2; ++pass) {
    int row = pass * 16 + (tid >> 4);
    int c4 = (tid & 15) * 4;
    float m0 = mls[0][0][row], m1 = mls[1][0][row];
    float m2 = mls[2][0][row], m3 = mls[3][0][row];
    float M = fmaxf(fmaxf(m0, m1), fmaxf(m2, m3));
    float s0 = __expf(m0 - M), s1 = __expf(m1 - M);
    float s2 = __expf(m2 - M), s3 = __expf(m3 - M);
    float L = s0 * mls[0][1][row] + s1 * mls[1][1][row]
            + s2 * mls[2][1][row] + s3 * mls[3][1][row];
    f32x4 a0 = *(const f32x4*)&accs[0][row][c4];
    f32x4 a1 = *(const f32x4*)&accs[1][row][c4];
    f32x4 a2 = *(const f32x4*)&accs[2][row][c4];
    f32x4 a3 = *(const f32x4*)&accs[3][row][c4];
    float inv = 1.f / L;
    f32x4 o;
#pragma unroll
    for (int j = 0; j < 4; ++j)
      o[j] = (s0 * a0[j] + s1 * a1[j] + s2 * a2[j] + s3 * a3[j]) * inv;
    *(f32x4*)(out + (size_t)(b * T_ + qbase + row) * DQ + c4) = o;
  }
}

extern "C" void kernel_launch(void* const* d_in, const int* in_sizes, int n_in,
                              void* d_out, int out_size, void* d_ws, size_t ws_size,
                              hipStream_t stream)
{
  const float* x  = (const float*)d_in[0];
  const float* Wq = (const float*)d_in[1];
  const float* Wk = (const float*)d_in[2];
  const float* Wv = (const float*)d_in[3];
  float* out = (float*)d_out;

  char* ws = (char*)d_ws;
  __bf16* Wf = (__bf16*)(ws);                                   // 384 KiB
  __bf16* Qb = (__bf16*)(ws + 0x80000);                         // 2 MiB
  __bf16* Kb = (__bf16*)(ws + 0x80000 + 0x200000);              // 2 MiB
  __bf16* Vt = (__bf16*)(ws + 0x80000 + 0x400000);              // 2 MiB

  kw_pack<<<96, 256, 0, stream>>>(Wq, Wk, Wv, Wf);
  kproj<<<512, 256, 0, stream>>>(x, Wf, Qb, Kb, Vt);
  kattn<<<512, 256, 0, stream>>>(Qb, Kb, Vt, out);
}

// Round 11
// 47.454 us; speedup vs baseline: 1.1223x; 1.1223x over previous
//
#include <hip/hip_runtime.h>

typedef float f32x4 __attribute__((ext_vector_type(4)));
typedef __bf16 bf16x8 __attribute__((ext_vector_type(8)));
typedef __bf16 bf16x4 __attribute__((ext_vector_type(4)));

#define T_ 2048
#define DE 1024
#define DQ 64
#define SCALE 0.125f

#define GL16(gp, lp)                                                        \
  __builtin_amdgcn_global_load_lds(                                         \
      (const __attribute__((address_space(1))) void*)(gp),                  \
      (__attribute__((address_space(3))) void*)(lp), 16, 0, 0)

#define WAITVM(N) asm volatile("s_waitcnt vmcnt(" #N ")" ::: "memory")

// ---------- kernel 0: pack W (3x [1024][64] f32) into fragment-major bf16 Wf.
// Wf[(kc*12 + t)*64 + lane][8]: elem j = W[kc*32+(lane>>4)*8+j][(t&3)*16+(lane&15)],
// matrix = t>>2, kc = k/32.  (validated R5-R10)
__global__ __launch_bounds__(256) void kw_pack(
    const float* __restrict__ Wq, const float* __restrict__ Wk,
    const float* __restrict__ Wv, __bf16* __restrict__ Wf)
{
  int tid = blockIdx.x * 256 + threadIdx.x;   // 0..24575 = f*64 + lane
  int lane = tid & 63, f = tid >> 6;
  int t = f % 12, kc = f / 12;
  const float* W = (t < 4) ? Wq : ((t < 8) ? Wk : Wv);
  int nl = (t & 3) * 16 + (lane & 15);
  int k0 = kc * 32 + (lane >> 4) * 8;
  bf16x8 v;
#pragma unroll
  for (int j = 0; j < 8; ++j) v[j] = (__bf16)W[(size_t)(k0 + j) * 64 + nl];
  *(bf16x8*)(Wf + (size_t)tid * 8) = v;
}

// ---------- kernel 1: QKV projection (R9 verbatim — best measured ~26us).
// Counted-vmcnt pipeline: A (x, HBM) 3 buffers staged 2 ahead; B (Wf, L2) 2 buffers
// staged 1 ahead. Per iter: vmcnt(2) -> s_barrier -> issue next stages -> compute.
__global__ __launch_bounds__(256) void kproj(
    const float* __restrict__ x, const __bf16* __restrict__ Wf,
    __bf16* __restrict__ Qb, __bf16* __restrict__ Kb, __bf16* __restrict__ Vt)
{
  __shared__ char lds[3 * 8192 + 2 * 24576];  // A: [0,24K)  B: [24K,72K)
  const int tid = threadIdx.x;
  const int lane = tid & 63;
  const int w = tid >> 6;
  const int col = lane & 15, g = lane >> 4;
  const int msub = w & 1;
  const int ng = w >> 1;
  const int mbase = blockIdx.x * 32;

  size_t gsrcA[2];
  int ldstA[2];
#pragma unroll
  for (int cc = 0; cc < 2; ++cc) {
    int q = w * 2 + cc;
    int row = q * 4 + (lane >> 4);
    int kbyte = ((lane & 15) * 16) ^ ((row & 7) << 4);
    gsrcA[cc] = (size_t)(mbase + row) * 4096 + (size_t)kbyte;
    ldstA[cc] = q * 1024 + lane * 16;
  }
  int ofsB[6];
#pragma unroll
  for (int cc = 0; cc < 6; ++cc) ofsB[cc] = (w * 6 + cc) * 1024 + lane * 16;

  f32x4 acc[6];
#pragma unroll
  for (int i = 0; i < 6; ++i) acc[i] = (f32x4){0.f, 0.f, 0.f, 0.f};

  const char* xb = (const char*)x;
  const char* wb = (const char*)Wf;

#define STAGE_A(ks)                                                         \
  {                                                                         \
    char* lb = &lds[((ks) % 3) * 8192];                                     \
    _Pragma("unroll")                                                       \
    for (int cc = 0; cc < 2; ++cc)                                          \
      GL16(xb + gsrcA[cc] + (size_t)(ks) * 256, lb + ldstA[cc]);            \
  }
#define STAGE_B(ks)                                                         \
  {                                                                         \
    char* lb = &lds[24576 + ((ks) & 1) * 24576];                            \
    _Pragma("unroll")                                                       \
    for (int cc = 0; cc < 6; ++cc)                                          \
      GL16(wb + (size_t)(ks) * 24576 + ofsB[cc], lb + ofsB[cc]);            \
  }
#define KSTEP(ks)                                                           \
  {                                                                         \
    const char* la = &lds[((ks) % 3) * 8192];                               \
    const char* lbB = &lds[24576 + ((ks) & 1) * 24576];                     \
    const int arow = msub * 16 + col;                                       \
    const char* abase = la + arow * 256;                                    \
    const int sw = (arow & 7) << 4;                                         \
    _Pragma("unroll")                                                       \
    for (int kh = 0; kh < 2; ++kh) {                                        \
      int kb = kh * 128 + g * 32;                                           \
      f32x4 a0 = *(const f32x4*)(abase + (kb ^ sw));                        \
      f32x4 a1 = *(const f32x4*)(abase + ((kb + 16) ^ sw));                 \
      bf16x8 af;                                                            \
      _Pragma("unroll")                                                     \
      for (int j = 0; j < 4; ++j) { af[j] = (__bf16)a0[j]; af[4 + j] = (__bf16)a1[j]; } \
      _Pragma("unroll")                                                     \
      for (int ii = 0; ii < 6; ++ii) {                                      \
        int nt = ng * 6 + ii;                                               \
        bf16x8 bfr = *(const bf16x8*)(lbB + ((kh * 12 + nt) * 64 + lane) * 16); \
        acc[ii] = __builtin_amdgcn_mfma_f32_16x16x32_bf16(af, bfr, acc[ii], 0, 0, 0); \
      }                                                                     \
    }                                                                       \
  }
#define ITER(ks, vm, doB, doA)                                              \
  WAITVM(vm);                                                               \
  __builtin_amdgcn_s_barrier();                                             \
  __builtin_amdgcn_sched_barrier(0);                                        \
  if (doB) STAGE_B((ks) + 1);                                               \
  if (doA) STAGE_A((ks) + 2);                                               \
  KSTEP(ks);

  STAGE_A(0);
  STAGE_B(0);
  STAGE_A(1);

  ITER(0, 2, 1, 1)  ITER(1, 2, 1, 1)  ITER(2, 2, 1, 1)  ITER(3, 2, 1, 1)
  ITER(4, 2, 1, 1)  ITER(5, 2, 1, 1)  ITER(6, 2, 1, 1)  ITER(7, 2, 1, 1)
  ITER(8, 2, 1, 1)  ITER(9, 2, 1, 1)  ITER(10, 2, 1, 1) ITER(11, 2, 1, 1)
  ITER(12, 2, 1, 1) ITER(13, 2, 1, 1) ITER(14, 2, 1, 0) ITER(15, 0, 0, 0)

#undef ITER
#undef KSTEP
#undef STAGE_B
#undef STAGE_A

  const int b = mbase >> 11;
  const int mrow = mbase + msub * 16 + g * 4;
  const int trow = (mbase & 2047) + msub * 16 + g * 4;
#pragma unroll
  for (int ii = 0; ii < 6; ++ii) {
    int ti = ng * 6 + ii;
    if (ti < 8) {
      __bf16* dst = (ti < 4) ? Qb : Kb;
      int c = (ti & 3) * 16 + col;
#pragma unroll
      for (int r = 0; r < 4; ++r)
        dst[(size_t)(mrow + r) * DQ + c] = (__bf16)acc[ii][r];
    } else {
      int d = (ti - 8) * 16 + col;
      bf16x4 v;
#pragma unroll
      for (int r = 0; r < 4; ++r) v[r] = (__bf16)acc[ii][r];
      *(bf16x4*)(Vt + ((size_t)(b * DQ + d)) * T_ + trow) = v;
    }
  }
}

// ---------- kernel 2: causal flash attention. Block = 32 q-rows, 4 waves split KV
// (KVB=64). NEW: wave-private K staging via global_load_lds, single 8KB buffer,
// distance-1 prefetch, zero barriers in loop. XOR-swizzled K tile (2-way banks).
// V-reg loads issued AFTER the K GL16s: the compiler's V-wait retires K(it+4)
// in-order, guaranteeing it landed before next iter's ds_read. Defer-max softmax.
__global__ __launch_bounds__(256) void kattn(
    const __bf16* __restrict__ Qb, const __bf16* __restrict__ Kb,
    const __bf16* __restrict__ Vt, float* __restrict__ out)
{
  // smem layout:
  //   [w*8704, w*8704+8192)  : wave w's K tile (loop phase)
  //   [w*8704, w*8704+8704)  : wave w's accs [32][68] f32 (post-loop, aliases kbuf)
  //   [34816 + w*4608, ...)  : wave w's plds [2][16][72] bf16
  //   [53248, 54272)         : mls [4][2][32] f32
  __shared__ char smem[54272];
  const int tid = threadIdx.x;
  const int lane = tid & 63;
  const int w = tid >> 6;
  const int col = lane & 15, g = lane >> 4;
  const int b = blockIdx.x & 7;
  const int jq = 63 - (blockIdx.x >> 3);
  const int qbase = jq * 32;

  char* kbuf = smem + w * 8704;
  __bf16* pld = (__bf16*)(smem + 34816 + w * 4608);   // [2][16][72]
  float* mls = (float*)(smem + 53248);                // [4][2][32]

  bf16x8 qa[2][2];
#pragma unroll
  for (int mt = 0; mt < 2; ++mt) {
    const __bf16* Qp = Qb + (size_t)(b * T_ + qbase + mt * 16 + col) * DQ + g * 8;
    qa[mt][0] = *(const bf16x8*)(Qp);
    qa[mt][1] = *(const bf16x8*)(Qp + 32);
  }

  const char* Kbb = (const char*)(Kb + (size_t)b * T_ * DQ);
  const __bf16* Vbb = Vt + (size_t)b * DQ * T_;

  // K staging map: 8 chunks x 16B/lane; linear LDS dest, pre-swizzled global src.
  size_t gofK[8];
  int lofK[8];
#pragma unroll
  for (int c = 0; c < 8; ++c) {
    int o = (c * 64 + lane) * 16;
    int row = o >> 7, slot = (o >> 4) & 7;
    lofK[c] = o;
    gofK[c] = (size_t)row * 128 + (size_t)((slot * 16) ^ ((row & 7) << 4));
  }

  f32x4 acc[2][4];
#pragma unroll
  for (int mt = 0; mt < 2; ++mt)
#pragma unroll
    for (int dt = 0; dt < 4; ++dt) acc[mt][dt] = (f32x4){0.f,0.f,0.f,0.f};
  float mrun[2][4], lsum[2][4];
#pragma unroll
  for (int mt = 0; mt < 2; ++mt)
#pragma unroll
    for (int r = 0; r < 4; ++r) { mrun[mt][r] = -1e30f; lsum[mt][r] = 0.f; }

  const int nb = (jq >> 1) + 1;

  // prologue: stage this wave's first K tile
  if (w < nb) {
    const char* src = Kbb + (size_t)(w * 64) * 128;
#pragma unroll
    for (int c = 0; c < 8; ++c) GL16(src + gofK[c], kbuf + lofK[c]);
  }
  WAITVM(0);
  __builtin_amdgcn_sched_barrier(0);

  for (int it = w; it < nb; it += 4) {
    const int nbase = it * 64;

    // K fragments from swizzled LDS tile
    bf16x8 kf_[4][2];
#pragma unroll
    for (int nt = 0; nt < 4; ++nt)
#pragma unroll
      for (int h = 0; h < 2; ++h) {
        int krow = nt * 16 + col;
        int bo = krow * 128 + ((h * 64 + g * 16) ^ ((krow & 7) << 4));
        kf_[nt][h] = *(const bf16x8*)(kbuf + bo);
      }
    asm volatile("s_waitcnt lgkmcnt(0)" ::: "memory");
    __builtin_amdgcn_sched_barrier(0);

    // prefetch next K tile into the same buffer (reads above are complete)
    if (it + 4 < nb) {
      const char* src = Kbb + (size_t)((it + 4) * 64) * 128;
#pragma unroll
      for (int c = 0; c < 8; ++c) GL16(src + gofK[c], kbuf + lofK[c]);
    }
    __builtin_amdgcn_sched_barrier(0);

    // V loads AFTER the GL16s (their wait retires the K prefetch in-order)
    bf16x8 vf[4][2];
#pragma unroll
    for (int dt = 0; dt < 4; ++dt) {
      const __bf16* Vp = Vbb + (size_t)(dt * 16 + col) * T_ + nbase + g * 8;
      vf[dt][0] = *(const bf16x8*)(Vp);
      vf[dt][1] = *(const bf16x8*)(Vp + 32);
    }

    f32x4 s[2][4];
#pragma unroll
    for (int mt = 0; mt < 2; ++mt)
#pragma unroll
      for (int nt = 0; nt < 4; ++nt) {
        f32x4 t = __builtin_amdgcn_mfma_f32_16x16x32_bf16(qa[mt][0], kf_[nt][0],
                                                          (f32x4){0.f,0.f,0.f,0.f}, 0, 0, 0);
        s[mt][nt] = __builtin_amdgcn_mfma_f32_16x16x32_bf16(qa[mt][1], kf_[nt][1], t, 0, 0, 0);
      }

#pragma unroll
    for (int mt = 0; mt < 2; ++mt)
#pragma unroll
      for (int nt = 0; nt < 4; ++nt)
#pragma unroll
        for (int r = 0; r < 4; ++r) s[mt][nt][r] *= SCALE;
    if (it == nb - 1) {
#pragma unroll
      for (int mt = 0; mt < 2; ++mt)
#pragma unroll
        for (int nt = 0; nt < 4; ++nt)
#pragma unroll
          for (int r = 0; r < 4; ++r)
            if (nbase + nt * 16 + col > qbase + mt * 16 + g * 4 + r) s[mt][nt][r] = -1e30f;
    }

    // defer-max online softmax
    float pmax[2][4];
#pragma unroll
    for (int mt = 0; mt < 2; ++mt)
#pragma unroll
      for (int r = 0; r < 4; ++r)
        pmax[mt][r] = fmaxf(fmaxf(s[mt][0][r], s[mt][1][r]), fmaxf(s[mt][2][r], s[mt][3][r]));
    bool need = false;
#pragma unroll
    for (int mt = 0; mt < 2; ++mt)
#pragma unroll
      for (int r = 0; r < 4; ++r)
        need = need || (pmax[mt][r] > mrun[mt][r] + 8.f);

    if (__any(need)) {
      float mv[2][4];
#pragma unroll
      for (int mt = 0; mt < 2; ++mt)
#pragma unroll
        for (int r = 0; r < 4; ++r) mv[mt][r] = pmax[mt][r];
#pragma unroll
      for (int sh = 1; sh <= 8; sh <<= 1)
#pragma unroll
        for (int mt = 0; mt < 2; ++mt)
#pragma unroll
          for (int r = 0; r < 4; ++r) mv[mt][r] = fmaxf(mv[mt][r], __shfl_xor(mv[mt][r], sh, 64));
#pragma unroll
      for (int mt = 0; mt < 2; ++mt)
#pragma unroll
        for (int r = 0; r < 4; ++r) {
          float mn = fmaxf(mrun[mt][r], mv[mt][r]);
          float rs = __expf(mrun[mt][r] - mn);
          mrun[mt][r] = mn;
          float ps = 0.f;
#pragma unroll
          for (int nt = 0; nt < 4; ++nt) {
            s[mt][nt][r] = __expf(s[mt][nt][r] - mn);
            ps += s[mt][nt][r];
          }
          lsum[mt][r] = lsum[mt][r] * rs + ps;
#pragma unroll
          for (int dt = 0; dt < 4; ++dt) acc[mt][dt][r] *= rs;
        }
    } else {
#pragma unroll
      for (int mt = 0; mt < 2; ++mt)
#pragma unroll
        for (int r = 0; r < 4; ++r) {
          float ps = 0.f;
#pragma unroll
          for (int nt = 0; nt < 4; ++nt) {
            s[mt][nt][r] = __expf(s[mt][nt][r] - mrun[mt][r]);
            ps += s[mt][nt][r];
          }
          lsum[mt][r] += ps;
        }
    }

    // P: D-layout -> A-layout via wave-private LDS
#pragma unroll
    for (int mt = 0; mt < 2; ++mt)
#pragma unroll
      for (int nt = 0; nt < 4; ++nt)
#pragma unroll
        for (int r = 0; r < 4; ++r)
          pld[(mt * 16 + g * 4 + r) * 72 + nt * 16 + col] = (__bf16)s[mt][nt][r];

    bf16x8 pa[2][2];
#pragma unroll
    for (int mt = 0; mt < 2; ++mt) {
      pa[mt][0] = *(const bf16x8*)&pld[(mt * 16 + col) * 72 + g * 8];
      pa[mt][1] = *(const bf16x8*)&pld[(mt * 16 + col) * 72 + 32 + g * 8];
    }

#pragma unroll
    for (int mt = 0; mt < 2; ++mt)
#pragma unroll
      for (int dt = 0; dt < 4; ++dt) {
        f32x4 t = __builtin_amdgcn_mfma_f32_16x16x32_bf16(pa[mt][0], vf[dt][0], acc[mt][dt], 0, 0, 0);
        acc[mt][dt] = __builtin_amdgcn_mfma_f32_16x16x32_bf16(pa[mt][1], vf[dt][1], t, 0, 0, 0);
      }
  }

#pragma unroll
  for (int sh = 1; sh <= 8; sh <<= 1)
#pragma unroll
    for (int mt = 0; mt < 2; ++mt)
#pragma unroll
      for (int r = 0; r < 4; ++r) lsum[mt][r] += __shfl_xor(lsum[mt][r], sh, 64);

  // publish per-wave partials into this wave's slab (aliases its dead kbuf)
  float* accw = (float*)(smem + w * 8704);
#pragma unroll
  for (int mt = 0; mt < 2; ++mt)
#pragma unroll
    for (int r = 0; r < 4; ++r) {
      int row = mt * 16 + g * 4 + r;
      accw[row * 68 + col]      = acc[mt][0][r];
      accw[row * 68 + col + 16] = acc[mt][1][r];
      accw[row * 68 + col + 32] = acc[mt][2][r];
      accw[row * 68 + col + 48] = acc[mt][3][r];
      if (col == 0) { mls[(w * 2 + 0) * 32 + row] = mrun[mt][r]; mls[(w * 2 + 1) * 32 + row] = lsum[mt][r]; }
    }
  __syncthreads();

#pragma unroll
  for (int pass = 0; pass < 2; ++pass) {
    int row = pass * 16 + (tid >> 4);
    int c4 = (tid & 15) * 4;
    float m0 = mls[0 * 32 + row], m1 = mls[2 * 32 + row];
    float m2 = mls[4 * 32 + row], m3 = mls[6 * 32 + row];
    float M = fmaxf(fmaxf(m0, m1), fmaxf(m2, m3));
    float s0 = __expf(m0 - M), s1 = __expf(m1 - M);
    float s2 = __expf(m2 - M), s3 = __expf(m3 - M);
    float L = s0 * mls[1 * 32 + row] + s1 * mls[3 * 32 + row]
            + s2 * mls[5 * 32 + row] + s3 * mls[7 * 32 + row];
    f32x4 a0 = *(const f32x4*)((float*)(smem + 0 * 8704) + row * 68 + c4);
    f32x4 a1 = *(const f32x4*)((float*)(smem + 1 * 8704) + row * 68 + c4);
    f32x4 a2 = *(const f32x4*)((float*)(smem + 2 * 8704) + row * 68 + c4);
    f32x4 a3 = *(const f32x4*)((float*)(smem + 3 * 8704) + row * 68 + c4);
    float inv = 1.f / L;
    f32x4 o;
#pragma unroll
    for (int j = 0; j < 4; ++j)
      o[j] = (s0 * a0[j] + s1 * a1[j] + s2 * a2[j] + s3 * a3[j]) * inv;
    *(f32x4*)(out + (size_t)(b * T_ + qbase + row) * DQ + c4) = o;
  }
}

extern "C" void kernel_launch(void* const* d_in, const int* in_sizes, int n_in,
                              void* d_out, int out_size, void* d_ws, size_t ws_size,
                              hipStream_t stream)
{
  const float* x  = (const float*)d_in[0];
  const float* Wq = (const float*)d_in[1];
  const float* Wk = (const float*)d_in[2];
  const float* Wv = (const float*)d_in[3];
  float* out = (float*)d_out;

  char* ws = (char*)d_ws;
  __bf16* Wf = (__bf16*)(ws);                                   // 384 KiB
  __bf16* Qb = (__bf16*)(ws + 0x80000);                         // 2 MiB
  __bf16* Kb = (__bf16*)(ws + 0x80000 + 0x200000);              // 2 MiB
  __bf16* Vt = (__bf16*)(ws + 0x80000 + 0x400000);              // 2 MiB

  kw_pack<<<96, 256, 0, stream>>>(Wq, Wk, Wv, Wf);
  kproj<<<512, 256, 0, stream>>>(x, Wf, Qb, Kb, Vt);
  kattn<<<512, 256, 0, stream>>>(Qb, Kb, Vt, out);
}

// Round 12
// 46.826 us; speedup vs baseline: 1.1374x; 1.0134x over previous
//
#include <hip/hip_runtime.h>

typedef float f32x4 __attribute__((ext_vector_type(4)));
typedef __bf16 bf16x8 __attribute__((ext_vector_type(8)));
typedef __bf16 bf16x4 __attribute__((ext_vector_type(4)));

#define T_ 2048
#define DE 1024
#define DQ 64
#define SCALE 0.125f

#define GL16(gp, lp)                                                        \
  __builtin_amdgcn_global_load_lds(                                         \
      (const __attribute__((address_space(1))) void*)(gp),                  \
      (__attribute__((address_space(3))) void*)(lp), 16, 0, 0)

#define WAITVM(N) asm volatile("s_waitcnt vmcnt(" #N ")" ::: "memory")

// ---------- kernel 0: pack W (3x [1024][64] f32) into fragment-major bf16 Wf.
__global__ __launch_bounds__(256) void kw_pack(
    const float* __restrict__ Wq, const float* __restrict__ Wk,
    const float* __restrict__ Wv, __bf16* __restrict__ Wf)
{
  int tid = blockIdx.x * 256 + threadIdx.x;   // 0..24575 = f*64 + lane
  int lane = tid & 63, f = tid >> 6;
  int t = f % 12, kc = f / 12;
  const float* W = (t < 4) ? Wq : ((t < 8) ? Wk : Wv);
  int nl = (t & 3) * 16 + (lane & 15);
  int k0 = kc * 32 + (lane >> 4) * 8;
  bf16x8 v;
#pragma unroll
  for (int j = 0; j < 8; ++j) v[j] = (__bf16)W[(size_t)(k0 + j) * 64 + nl];
  *(bf16x8*)(Wf + (size_t)tid * 8) = v;
}

// ---------- kernel 1: QKV projection (R9 verbatim — best measured ~26us).
__global__ __launch_bounds__(256) void kproj(
    const float* __restrict__ x, const __bf16* __restrict__ Wf,
    __bf16* __restrict__ Qb, __bf16* __restrict__ Kb, __bf16* __restrict__ Vt)
{
  __shared__ char lds[3 * 8192 + 2 * 24576];  // A: [0,24K)  B: [24K,72K)
  const int tid = threadIdx.x;
  const int lane = tid & 63;
  const int w = tid >> 6;
  const int col = lane & 15, g = lane >> 4;
  const int msub = w & 1;
  const int ng = w >> 1;
  const int mbase = blockIdx.x * 32;

  size_t gsrcA[2];
  int ldstA[2];
#pragma unroll
  for (int cc = 0; cc < 2; ++cc) {
    int q = w * 2 + cc;
    int row = q * 4 + (lane >> 4);
    int kbyte = ((lane & 15) * 16) ^ ((row & 7) << 4);
    gsrcA[cc] = (size_t)(mbase + row) * 4096 + (size_t)kbyte;
    ldstA[cc] = q * 1024 + lane * 16;
  }
  int ofsB[6];
#pragma unroll
  for (int cc = 0; cc < 6; ++cc) ofsB[cc] = (w * 6 + cc) * 1024 + lane * 16;

  f32x4 acc[6];
#pragma unroll
  for (int i = 0; i < 6; ++i) acc[i] = (f32x4){0.f, 0.f, 0.f, 0.f};

  const char* xb = (const char*)x;
  const char* wb = (const char*)Wf;

#define STAGE_A(ks)                                                         \
  {                                                                         \
    char* lb = &lds[((ks) % 3) * 8192];                                     \
    _Pragma("unroll")                                                       \
    for (int cc = 0; cc < 2; ++cc)                                          \
      GL16(xb + gsrcA[cc] + (size_t)(ks) * 256, lb + ldstA[cc]);            \
  }
#define STAGE_B(ks)                                                         \
  {                                                                         \
    char* lb = &lds[24576 + ((ks) & 1) * 24576];                            \
    _Pragma("unroll")                                                       \
    for (int cc = 0; cc < 6; ++cc)                                          \
      GL16(wb + (size_t)(ks) * 24576 + ofsB[cc], lb + ofsB[cc]);            \
  }
#define KSTEP(ks)                                                           \
  {                                                                         \
    const char* la = &lds[((ks) % 3) * 8192];                               \
    const char* lbB = &lds[24576 + ((ks) & 1) * 24576];                     \
    const int arow = msub * 16 + col;                                       \
    const char* abase = la + arow * 256;                                    \
    const int sw = (arow & 7) << 4;                                         \
    _Pragma("unroll")                                                       \
    for (int kh = 0; kh < 2; ++kh) {                                        \
      int kb = kh * 128 + g * 32;                                           \
      f32x4 a0 = *(const f32x4*)(abase + (kb ^ sw));                        \
      f32x4 a1 = *(const f32x4*)(abase + ((kb + 16) ^ sw));                 \
      bf16x8 af;                                                            \
      _Pragma("unroll")                                                     \
      for (int j = 0; j < 4; ++j) { af[j] = (__bf16)a0[j]; af[4 + j] = (__bf16)a1[j]; } \
      _Pragma("unroll")                                                     \
      for (int ii = 0; ii < 6; ++ii) {                                      \
        int nt = ng * 6 + ii;                                               \
        bf16x8 bfr = *(const bf16x8*)(lbB + ((kh * 12 + nt) * 64 + lane) * 16); \
        acc[ii] = __builtin_amdgcn_mfma_f32_16x16x32_bf16(af, bfr, acc[ii], 0, 0, 0); \
      }                                                                     \
    }                                                                       \
  }
#define ITER(ks, vm, doB, doA)                                              \
  WAITVM(vm);                                                               \
  __builtin_amdgcn_s_barrier();                                             \
  __builtin_amdgcn_sched_barrier(0);                                        \
  if (doB) STAGE_B((ks) + 1);                                               \
  if (doA) STAGE_A((ks) + 2);                                               \
  KSTEP(ks);

  STAGE_A(0);
  STAGE_B(0);
  STAGE_A(1);

  ITER(0, 2, 1, 1)  ITER(1, 2, 1, 1)  ITER(2, 2, 1, 1)  ITER(3, 2, 1, 1)
  ITER(4, 2, 1, 1)  ITER(5, 2, 1, 1)  ITER(6, 2, 1, 1)  ITER(7, 2, 1, 1)
  ITER(8, 2, 1, 1)  ITER(9, 2, 1, 1)  ITER(10, 2, 1, 1) ITER(11, 2, 1, 1)
  ITER(12, 2, 1, 1) ITER(13, 2, 1, 1) ITER(14, 2, 1, 0) ITER(15, 0, 0, 0)

#undef ITER
#undef KSTEP
#undef STAGE_B
#undef STAGE_A

  const int b = mbase >> 11;
  const int mrow = mbase + msub * 16 + g * 4;
  const int trow = (mbase & 2047) + msub * 16 + g * 4;
#pragma unroll
  for (int ii = 0; ii < 6; ++ii) {
    int ti = ng * 6 + ii;
    if (ti < 8) {
      __bf16* dst = (ti < 4) ? Qb : Kb;
      int c = (ti & 3) * 16 + col;
#pragma unroll
      for (int r = 0; r < 4; ++r)
        dst[(size_t)(mrow + r) * DQ + c] = (__bf16)acc[ii][r];
    } else {
      int d = (ti - 8) * 16 + col;
      bf16x4 v;
#pragma unroll
      for (int r = 0; r < 4; ++r) v[r] = (__bf16)acc[ii][r];
      *(bf16x4*)(Vt + ((size_t)(b * DQ + d)) * T_ + trow) = v;
    }
  }
}

// ---------- kernel 2: causal flash attention. Block = 32 q-rows, 4 waves split KV
// (KVB=64). K AND V wave-private staged via global_load_lds (XOR-swizzled,
// distance-1 prefetch, zero barriers in loop, zero global latency in the chain).
__global__ __launch_bounds__(256) void kattn(
    const __bf16* __restrict__ Qb, const __bf16* __restrict__ Kb,
    const __bf16* __restrict__ Vt, float* __restrict__ out)
{
  // smem: [w*16384, +8192) kbuf | [+8192, +16384) vbuf (accs alias kbuf post-loop)
  //       [65536 + w*4608) plds [2][16][72] bf16 | [83968) mls [4][2][32] f32
  __shared__ char smem[84992];
  const int tid = threadIdx.x;
  const int lane = tid & 63;
  const int w = tid >> 6;
  const int col = lane & 15, g = lane >> 4;
  const int b = blockIdx.x & 7;
  const int jq = 63 - (blockIdx.x >> 3);
  const int qbase = jq * 32;

  char* kbuf = smem + w * 16384;
  char* vbuf = kbuf + 8192;
  __bf16* pld = (__bf16*)(smem + 65536 + w * 4608);
  float* mls = (float*)(smem + 83968);

  bf16x8 qa[2][2];
#pragma unroll
  for (int mt = 0; mt < 2; ++mt) {
    const __bf16* Qp = Qb + (size_t)(b * T_ + qbase + mt * 16 + col) * DQ + g * 8;
    qa[mt][0] = *(const bf16x8*)(Qp);
    qa[mt][1] = *(const bf16x8*)(Qp + 32);
  }

  const char* Kbb = (const char*)(Kb + (size_t)b * T_ * DQ);
  const char* Vbb = (const char*)(Vt + (size_t)b * DQ * T_);

  // staging maps: linear LDS dest (row*128 + slot*16); global source pre-swizzled
  // by ((row&7)<<4). K tile rows stride 128B; V (Vt[d][T]) rows stride 4096B.
  size_t gofK[8], gofV[8];
  int lof[8];
#pragma unroll
  for (int c = 0; c < 8; ++c) {
    int o = (c * 64 + lane) * 16;
    int row = o >> 7, slot = (o >> 4) & 7;
    int sl = (slot * 16) ^ ((row & 7) << 4);
    lof[c] = o;
    gofK[c] = (size_t)row * 128 + sl;
    gofV[c] = (size_t)row * 4096 + sl;
  }

  f32x4 acc[2][4];
#pragma unroll
  for (int mt = 0; mt < 2; ++mt)
#pragma unroll
    for (int dt = 0; dt < 4; ++dt) acc[mt][dt] = (f32x4){0.f,0.f,0.f,0.f};
  float mrun[2][4], lsum[2][4];
#pragma unroll
  for (int mt = 0; mt < 2; ++mt)
#pragma unroll
    for (int r = 0; r < 4; ++r) { mrun[mt][r] = -1e30f; lsum[mt][r] = 0.f; }

  const int nb = (jq >> 1) + 1;

  // prologue: stage this wave's first K and V tiles
  if (w < nb) {
    const char* ksrc = Kbb + (size_t)(w * 64) * 128;
    const char* vsrc = Vbb + (size_t)(w * 64) * 2;
#pragma unroll
    for (int c = 0; c < 8; ++c) GL16(ksrc + gofK[c], kbuf + lof[c]);
#pragma unroll
    for (int c = 0; c < 8; ++c) GL16(vsrc + gofV[c], vbuf + lof[c]);
  }

  for (int it = w; it < nb; it += 4) {
    const int nbase = it * 64;

    WAITVM(0);                                // staged K/V for this iter landed
    __builtin_amdgcn_sched_barrier(0);

    // K + V fragments from swizzled LDS tiles
    bf16x8 kf_[4][2], vf[4][2];
#pragma unroll
    for (int nt = 0; nt < 4; ++nt)
#pragma unroll
      for (int h = 0; h < 2; ++h) {
        int krow = nt * 16 + col;
        int bo = krow * 128 + ((h * 64 + g * 16) ^ ((krow & 7) << 4));
        kf_[nt][h] = *(const bf16x8*)(kbuf + bo);
        vf[nt][h]  = *(const bf16x8*)(vbuf + bo);
      }
    asm volatile("s_waitcnt lgkmcnt(0)" ::: "memory");
    __builtin_amdgcn_sched_barrier(0);

    // prefetch next K/V tiles into the same buffers (reads above complete)
    if (it + 4 < nb) {
      const char* ksrc = Kbb + (size_t)((it + 4) * 64) * 128;
      const char* vsrc = Vbb + (size_t)((it + 4) * 64) * 2;
#pragma unroll
      for (int c = 0; c < 8; ++c) GL16(ksrc + gofK[c], kbuf + lof[c]);
#pragma unroll
      for (int c = 0; c < 8; ++c) GL16(vsrc + gofV[c], vbuf + lof[c]);
    }
    __builtin_amdgcn_sched_barrier(0);

    f32x4 s[2][4];
#pragma unroll
    for (int mt = 0; mt < 2; ++mt)
#pragma unroll
      for (int nt = 0; nt < 4; ++nt) {
        f32x4 t = __builtin_amdgcn_mfma_f32_16x16x32_bf16(qa[mt][0], kf_[nt][0],
                                                          (f32x4){0.f,0.f,0.f,0.f}, 0, 0, 0);
        s[mt][nt] = __builtin_amdgcn_mfma_f32_16x16x32_bf16(qa[mt][1], kf_[nt][1], t, 0, 0, 0);
      }

#pragma unroll
    for (int mt = 0; mt < 2; ++mt)
#pragma unroll
      for (int nt = 0; nt < 4; ++nt)
#pragma unroll
        for (int r = 0; r < 4; ++r) s[mt][nt][r] *= SCALE;
    if (it == nb - 1) {
#pragma unroll
      for (int mt = 0; mt < 2; ++mt)
#pragma unroll
        for (int nt = 0; nt < 4; ++nt)
#pragma unroll
          for (int r = 0; r < 4; ++r)
            if (nbase + nt * 16 + col > qbase + mt * 16 + g * 4 + r) s[mt][nt][r] = -1e30f;
    }

    // defer-max online softmax
    float pmax[2][4];
#pragma unroll
    for (int mt = 0; mt < 2; ++mt)
#pragma unroll
      for (int r = 0; r < 4; ++r)
        pmax[mt][r] = fmaxf(fmaxf(s[mt][0][r], s[mt][1][r]), fmaxf(s[mt][2][r], s[mt][3][r]));
    bool need = false;
#pragma unroll
    for (int mt = 0; mt < 2; ++mt)
#pragma unroll
      for (int r = 0; r < 4; ++r)
        need = need || (pmax[mt][r] > mrun[mt][r] + 8.f);

    if (__any(need)) {
      float mv[2][4];
#pragma unroll
      for (int mt = 0; mt < 2; ++mt)
#pragma unroll
        for (int r = 0; r < 4; ++r) mv[mt][r] = pmax[mt][r];
#pragma unroll
      for (int sh = 1; sh <= 8; sh <<= 1)
#pragma unroll
        for (int mt = 0; mt < 2; ++mt)
#pragma unroll
          for (int r = 0; r < 4; ++r) mv[mt][r] = fmaxf(mv[mt][r], __shfl_xor(mv[mt][r], sh, 64));
#pragma unroll
      for (int mt = 0; mt < 2; ++mt)
#pragma unroll
        for (int r = 0; r < 4; ++r) {
          float mn = fmaxf(mrun[mt][r], mv[mt][r]);
          float rs = __expf(mrun[mt][r] - mn);
          mrun[mt][r] = mn;
          float ps = 0.f;
#pragma unroll
          for (int nt = 0; nt < 4; ++nt) {
            s[mt][nt][r] = __expf(s[mt][nt][r] - mn);
            ps += s[mt][nt][r];
          }
          lsum[mt][r] = lsum[mt][r] * rs + ps;
#pragma unroll
          for (int dt = 0; dt < 4; ++dt) acc[mt][dt][r] *= rs;
        }
    } else {
#pragma unroll
      for (int mt = 0; mt < 2; ++mt)
#pragma unroll
        for (int r = 0; r < 4; ++r) {
          float ps = 0.f;
#pragma unroll
          for (int nt = 0; nt < 4; ++nt) {
            s[mt][nt][r] = __expf(s[mt][nt][r] - mrun[mt][r]);
            ps += s[mt][nt][r];
          }
          lsum[mt][r] += ps;
        }
    }

    // P: D-layout -> A-layout via wave-private LDS
#pragma unroll
    for (int mt = 0; mt < 2; ++mt)
#pragma unroll
      for (int nt = 0; nt < 4; ++nt)
#pragma unroll
        for (int r = 0; r < 4; ++r)
          pld[(mt * 16 + g * 4 + r) * 72 + nt * 16 + col] = (__bf16)s[mt][nt][r];

    bf16x8 pa[2][2];
#pragma unroll
    for (int mt = 0; mt < 2; ++mt) {
      pa[mt][0] = *(const bf16x8*)&pld[(mt * 16 + col) * 72 + g * 8];
      pa[mt][1] = *(const bf16x8*)&pld[(mt * 16 + col) * 72 + 32 + g * 8];
    }

#pragma unroll
    for (int mt = 0; mt < 2; ++mt)
#pragma unroll
      for (int dt = 0; dt < 4; ++dt) {
        f32x4 t = __builtin_amdgcn_mfma_f32_16x16x32_bf16(pa[mt][0], vf[dt][0], acc[mt][dt], 0, 0, 0);
        acc[mt][dt] = __builtin_amdgcn_mfma_f32_16x16x32_bf16(pa[mt][1], vf[dt][1], t, 0, 0, 0);
      }
  }

#pragma unroll
  for (int sh = 1; sh <= 8; sh <<= 1)
#pragma unroll
    for (int mt = 0; mt < 2; ++mt)
#pragma unroll
      for (int r = 0; r < 4; ++r) lsum[mt][r] += __shfl_xor(lsum[mt][r], sh, 64);

  // publish per-wave partials into this wave's slab (aliases its dead K/V bufs)
  float* accw = (float*)(smem + w * 16384);
#pragma unroll
  for (int mt = 0; mt < 2; ++mt)
#pragma unroll
    for (int r = 0; r < 4; ++r) {
      int row = mt * 16 + g * 4 + r;
      accw[row * 68 + col]      = acc[mt][0][r];
      accw[row * 68 + col + 16] = acc[mt][1][r];
      accw[row * 68 + col + 32] = acc[mt][2][r];
      accw[row * 68 + col + 48] = acc[mt][3][r];
      if (col == 0) { mls[(w * 2 + 0) * 32 + row] = mrun[mt][r]; mls[(w * 2 + 1) * 32 + row] = lsum[mt][r]; }
    }
  __syncthreads();

#pragma unroll
  for (int pass = 0; pass < 2; ++pass) {
    int row = pass * 16 + (tid >> 4);
    int c4 = (tid & 15) * 4;
    float m0 = mls[0 * 32 + row], m1 = mls[2 * 32 + row];
    float m2 = mls[4 * 32 + row], m3 = mls[6 * 32 + row];
    float M = fmaxf(fmaxf(m0, m1), fmaxf(m2, m3));
    float s0 = __expf(m0 - M), s1 = __expf(m1 - M);
    float s2 = __expf(m2 - M), s3 = __expf(m3 - M);
    float L = s0 * mls[1 * 32 + row] + s1 * mls[3 * 32 + row]
            + s2 * mls[5 * 32 + row] + s3 * mls[7 * 32 + row];
    f32x4 a0 = *(const f32x4*)((float*)(smem + 0 * 16384) + row * 68 + c4);
    f32x4 a1 = *(const f32x4*)((float*)(smem + 1 * 16384) + row * 68 + c4);
    f32x4 a2 = *(const f32x4*)((float*)(smem + 2 * 16384) + row * 68 + c4);
    f32x4 a3 = *(const f32x4*)((float*)(smem + 3 * 16384) + row * 68 + c4);
    float inv = 1.f / L;
    f32x4 o;
#pragma unroll
    for (int j = 0; j < 4; ++j)
      o[j] = (s0 * a0[j] + s1 * a1[j] + s2 * a2[j] + s3 * a3[j]) * inv;
    *(f32x4*)(out + (size_t)(b * T_ + qbase + row) * DQ + c4) = o;
  }
}

extern "C" void kernel_launch(void* const* d_in, const int* in_sizes, int n_in,
                              void* d_out, int out_size, void* d_ws, size_t ws_size,
                              hipStream_t stream)
{
  const float* x  = (const float*)d_in[0];
  const float* Wq = (const float*)d_in[1];
  const float* Wk = (const float*)d_in[2];
  const float* Wv = (const float*)d_in[3];
  float* out = (float*)d_out;

  char* ws = (char*)d_ws;
  __bf16* Wf = (__bf16*)(ws);                                   // 384 KiB
  __bf16* Qb = (__bf16*)(ws + 0x80000);                         // 2 MiB
  __bf16* Kb = (__bf16*)(ws + 0x80000 + 0x200000);              // 2 MiB
  __bf16* Vt = (__bf16*)(ws + 0x80000 + 0x400000);              // 2 MiB

  kw_pack<<<96, 256, 0, stream>>>(Wq, Wk, Wv, Wf);
  kproj<<<512, 256, 0, stream>>>(x, Wf, Qb, Kb, Vt);
  kattn<<<512, 256, 0, stream>>>(Qb, Kb, Vt, out);
}